// Round 1
// baseline (704.760 us; speedup 1.0000x reference)
//
#include <hip/hip_runtime.h>

#define NEG (-1e9f)

typedef __attribute__((ext_vector_type(8))) short bf16x8;
typedef __attribute__((ext_vector_type(4))) float f32x4;

static constexpr int Ss = 2048, Dd = 64;

__device__ __forceinline__ unsigned short f2bf(float f) {
  union { float f; unsigned u; } v; v.f = f;
  unsigned r = v.u + 0x7FFF + ((v.u >> 16) & 1);  // RTNE
  return (unsigned short)(r >> 16);
}

__global__ __launch_bounds__(256) void attn_kernel(
    const float* __restrict__ q, const float* __restrict__ k,
    const float* __restrict__ v, const int* __restrict__ mask,
    float* __restrict__ out, float* __restrict__ attn) {
  const int tid  = threadIdx.x;
  const int wave = tid >> 6;
  const int lane = tid & 63;
  const int quad = lane >> 4;
  const int ln15 = lane & 15;

  const int bh = blockIdx.x & 31;          // same bh -> same XCD (stride 32 ≡ 0 mod 8)
  const int qt = 31 - (blockIdx.x >> 5);   // big causal blocks dispatched first
  const int b  = bh >> 4;                  // H = 16

  __shared__ unsigned short Klds[64 * 72];
  __shared__ unsigned short Vlds[64 * 72];
  __shared__ unsigned short Plds[64 * 72];

  // ---- stage Q (scaled by 1/8, exact pow2) via Vlds, pull A-frags to regs ----
  {
    const float* qp = q + ((size_t)bh * Ss + (size_t)qt * 64) * Dd;
#pragma unroll
    for (int i = 0; i < 4; ++i) {
      int idx4 = tid + i * 256;
      int row = idx4 >> 4, col = (idx4 & 15) * 4;
      float4 f = *(const float4*)(qp + row * 64 + col);
      ushort4 u;
      u.x = f2bf(f.x * 0.125f); u.y = f2bf(f.y * 0.125f);
      u.z = f2bf(f.z * 0.125f); u.w = f2bf(f.w * 0.125f);
      *(ushort4*)&Vlds[row * 72 + col] = u;
    }
  }
  __syncthreads();
  const bf16x8 qfrag0 = *(const bf16x8*)&Vlds[(wave * 16 + ln15) * 72 + quad * 8];
  const bf16x8 qfrag1 = *(const bf16x8*)&Vlds[(wave * 16 + ln15) * 72 + quad * 8 + 32];

  float mrow[4], lrow[4];
#pragma unroll
  for (int r = 0; r < 4; ++r) { mrow[r] = -1e30f; lrow[r] = 0.0f; }

  // ---------------- pass 1: online max/sum ----------------
  for (int j = 0; j <= qt; ++j) {
    __syncthreads();
    {
      const float* kp = k + ((size_t)bh * Ss + (size_t)j * 64) * Dd;
#pragma unroll
      for (int i = 0; i < 4; ++i) {
        int idx4 = tid + i * 256;
        int row = idx4 >> 4, col = (idx4 & 15) * 4;
        float4 f = *(const float4*)(kp + row * 64 + col);
        ushort4 u;
        u.x = f2bf(f.x); u.y = f2bf(f.y); u.z = f2bf(f.z); u.w = f2bf(f.w);
        *(ushort4*)&Klds[row * 72 + col] = u;
      }
    }
    __syncthreads();
    unsigned long long mm = __ballot(mask[(size_t)b * Ss + j * 64 + lane] != 0);

    float sv[4][4];
#pragma unroll
    for (int c = 0; c < 4; ++c) {
      bf16x8 kf0 = *(const bf16x8*)&Klds[(c * 16 + ln15) * 72 + quad * 8];
      bf16x8 kf1 = *(const bf16x8*)&Klds[(c * 16 + ln15) * 72 + quad * 8 + 32];
      f32x4 acc = {0.f, 0.f, 0.f, 0.f};
      acc = __builtin_amdgcn_mfma_f32_16x16x32_bf16(qfrag0, kf0, acc, 0, 0, 0);
      acc = __builtin_amdgcn_mfma_f32_16x16x32_bf16(qfrag1, kf1, acc, 0, 0, 0);
      int col = j * 64 + c * 16 + ln15;
      bool mz = !((mm >> (c * 16 + ln15)) & 1);
#pragma unroll
      for (int r = 0; r < 4; ++r) {
        int row = qt * 64 + wave * 16 + quad * 4 + r;
        float val = acc[r];
        if (col > row || mz) val = NEG;
        sv[c][r] = val;
      }
    }
#pragma unroll
    for (int r = 0; r < 4; ++r) {
      float tm = fmaxf(fmaxf(sv[0][r], sv[1][r]), fmaxf(sv[2][r], sv[3][r]));
      tm = fmaxf(tm, __shfl_xor(tm, 1));
      tm = fmaxf(tm, __shfl_xor(tm, 2));
      tm = fmaxf(tm, __shfl_xor(tm, 4));
      tm = fmaxf(tm, __shfl_xor(tm, 8));
      float mnew = fmaxf(mrow[r], tm);
      float ss = __expf(sv[0][r] - mnew) + __expf(sv[1][r] - mnew) +
                 __expf(sv[2][r] - mnew) + __expf(sv[3][r] - mnew);
      ss += __shfl_xor(ss, 1);
      ss += __shfl_xor(ss, 2);
      ss += __shfl_xor(ss, 4);
      ss += __shfl_xor(ss, 8);
      lrow[r] = lrow[r] * __expf(mrow[r] - mnew) + ss;
      mrow[r] = mnew;
    }
  }

  float rl[4];
#pragma unroll
  for (int r = 0; r < 4; ++r) rl[r] = 1.0f / lrow[r];

  f32x4 oacc[4];
#pragma unroll
  for (int c = 0; c < 4; ++c) oacc[c] = (f32x4){0.f, 0.f, 0.f, 0.f};

  // ---------------- pass 2: recompute, write attn, accumulate O = P·V ----------------
  for (int j = 0; j < 32; ++j) {
    if (j <= qt) {
      __syncthreads();
      {
        const float* kp = k + ((size_t)bh * Ss + (size_t)j * 64) * Dd;
        const float* vp = v + ((size_t)bh * Ss + (size_t)j * 64) * Dd;
#pragma unroll
        for (int i = 0; i < 4; ++i) {
          int idx4 = tid + i * 256;
          int row = idx4 >> 4, col = (idx4 & 15) * 4;
          float4 f = *(const float4*)(kp + row * 64 + col);
          ushort4 u;
          u.x = f2bf(f.x); u.y = f2bf(f.y); u.z = f2bf(f.z); u.w = f2bf(f.w);
          *(ushort4*)&Klds[row * 72 + col] = u;
          float4 g = *(const float4*)(vp + row * 64 + col);
          ushort4 w2;
          w2.x = f2bf(g.x); w2.y = f2bf(g.y); w2.z = f2bf(g.z); w2.w = f2bf(g.w);
          *(ushort4*)&Vlds[row * 72 + col] = w2;
        }
      }
      __syncthreads();
      unsigned long long mm = __ballot(mask[(size_t)b * Ss + j * 64 + lane] != 0);
#pragma unroll
      for (int c = 0; c < 4; ++c) {
        bf16x8 kf0 = *(const bf16x8*)&Klds[(c * 16 + ln15) * 72 + quad * 8];
        bf16x8 kf1 = *(const bf16x8*)&Klds[(c * 16 + ln15) * 72 + quad * 8 + 32];
        f32x4 acc = {0.f, 0.f, 0.f, 0.f};
        acc = __builtin_amdgcn_mfma_f32_16x16x32_bf16(qfrag0, kf0, acc, 0, 0, 0);
        acc = __builtin_amdgcn_mfma_f32_16x16x32_bf16(qfrag1, kf1, acc, 0, 0, 0);
        int col = j * 64 + c * 16 + ln15;
        bool mz = !((mm >> (c * 16 + ln15)) & 1);
#pragma unroll
        for (int r = 0; r < 4; ++r) {
          int row = qt * 64 + wave * 16 + quad * 4 + r;
          float val = acc[r];
          if (col > row || mz) val = NEG;
          float p = __expf(val - mrow[r]) * rl[r];
          attn[((size_t)bh * Ss + row) * Ss + col] = p;
          // C-layout -> A-layout remap via LDS (own strip only: no barrier needed)
          Plds[(wave * 16 + quad * 4 + r) * 72 + c * 16 + ln15] = f2bf(p);
        }
      }
#pragma unroll
      for (int ch = 0; ch < 2; ++ch) {
        bf16x8 pf = *(const bf16x8*)&Plds[(wave * 16 + ln15) * 72 + quad * 8 + 32 * ch];
#pragma unroll
        for (int c = 0; c < 4; ++c) {
          bf16x8 vf;
#pragma unroll
          for (int jj = 0; jj < 8; ++jj)
            vf[jj] = (short)Vlds[(quad * 8 + jj + 32 * ch) * 72 + c * 16 + ln15];
          oacc[c] = __builtin_amdgcn_mfma_f32_16x16x32_bf16(pf, vf, oacc[c], 0, 0, 0);
        }
      }
    } else {
      // strictly above the diagonal: pure zero-fill, coalesced float4
      float4 z = {0.f, 0.f, 0.f, 0.f};
#pragma unroll
      for (int i = 0; i < 4; ++i) {
        int idx4 = tid + i * 256;
        int row = idx4 >> 4, col = (idx4 & 15) * 4;
        *(float4*)&attn[((size_t)bh * Ss + qt * 64 + row) * Ss + j * 64 + col] = z;
      }
    }
  }

  // ---- write O ----
#pragma unroll
  for (int c = 0; c < 4; ++c)
#pragma unroll
    for (int r = 0; r < 4; ++r) {
      int row = qt * 64 + wave * 16 + quad * 4 + r;
      out[((size_t)bh * Ss + row) * Dd + c * 16 + ln15] = oacc[c][r];
    }
}

extern "C" void kernel_launch(void* const* d_in, const int* in_sizes, int n_in,
                              void* d_out, int out_size, void* d_ws, size_t ws_size,
                              hipStream_t stream) {
  const float* q    = (const float*)d_in[0];
  const float* k    = (const float*)d_in[1];
  const float* v    = (const float*)d_in[2];
  const int*   mask = (const int*)d_in[3];
  float* out  = (float*)d_out;
  float* attn = out + (size_t)2 * 16 * 2048 * 64;  // out first, then attn
  attn_kernel<<<dim3(32 * 32), dim3(256), 0, stream>>>(q, k, v, mask, out, attn);
}